// Round 8
// baseline (180.844 us; speedup 1.0000x reference)
//
#include <hip/hip_runtime.h>
#include <hip/hip_bf16.h>

// HierarchicalEmbedding: per-token embedding gather + weighted digit accumulation.
//
// out[n, :] = mods[n]==2 ? E1[fidx]*vals[n]
//                        : E1[fidx] + sum_{i<ndigits[n]} (1/(i+2)^kappa) * Eint[digits[n,i]]
// fidx = mods==0 ? fc+5 : mods==1 ? 2*fc+5 : 52+fc
//
// R8: kill the per-token gather latency chain. icd/atc tokens (2/3) only ever
// touch E1 rows 5..56 (26.6 KB) -> stage that sub-table in LDS; main loop is
// then LDS-fed for 2/3 of tokens. Lab tokens (1/3) gather from L2, issued
// early & exec-masked. Wave halves handle ADJACENT tokens -> every store
// writes 1 KB contiguous. LDS 36.9 KB/block -> 4 blocks/CU (16 waves).

#define LM1 6
#define D   128
#define TPB 128  // tokens per block
#define TPT 4    // tokens per thread per chunk
#define NCHUNK (TPB / 32)   // 4 chunks of 32 tokens
#define E1LO   5
#define E1ROWS 52  // E1 rows 5..56 cover all icd/atc first-level indices

typedef float nfloat4 __attribute__((ext_vector_type(4)));

__global__ __launch_bounds__(256, 4) void hier_emb_kernel(
    const int*   __restrict__ first_chars,
    const int*   __restrict__ digits,
    const int*   __restrict__ ndigits,
    const int*   __restrict__ mods,
    const float* __restrict__ vals,
    const float* __restrict__ E1,
    const float* __restrict__ Eint,
    const int*   __restrict__ kappa_p,
    float*       __restrict__ out,
    int n)
{
    __shared__ float sE1[E1ROWS][D];     // 26.6 KB: E1 rows 5..56
    __shared__ float sEint[10][D];       // 5 KB: digit table
    __shared__ int   sFidx[TPB];         // global E1 row index per token
    __shared__ int   sNd[TPB];
    __shared__ int   sMod[TPB];
    __shared__ float sVal[TPB];
    __shared__ int   sDig[TPB * LM1];    // 3 KB

    const int tid  = threadIdx.x;
    const int tok0 = blockIdx.x * TPB;

    // --- Stage E1 sub-table: 52*128/4 = 1664 float4, 256 thr -> 7 rounds ---
    {
        const nfloat4* src = reinterpret_cast<const nfloat4*>(E1 + E1LO * D);
        nfloat4*       dst = reinterpret_cast<nfloat4*>(&sE1[0][0]);
#pragma unroll
        for (int r = 0; r < 7; ++r) {
            const int i = tid + r * 256;
            if (i < (E1ROWS * D) / 4) dst[i] = src[i];
        }
    }
    // --- Stage Eint: 320 float4 ---
    {
        const nfloat4* src = reinterpret_cast<const nfloat4*>(Eint);
        nfloat4*       dst = reinterpret_cast<nfloat4*>(&sEint[0][0]);
        dst[tid] = src[tid];
        const int i2 = 256 + tid;
        if (i2 < (10 * D) / 4) dst[i2] = src[i2];
    }
    // --- Stage per-token metadata (coalesced) ---
    if (tid < TPB) {
        int tt = tok0 + tid; if (tt >= n) tt = n - 1;
        const int mod = mods[tt];
        const int fc  = first_chars[tt];
        sMod[tid]  = mod;
        sFidx[tid] = (mod == 0) ? (fc + 5) : (mod == 1) ? (fc * 2 + 5) : (52 + fc);
        sNd[tid]   = ndigits[tt];
        sVal[tid]  = vals[tt];
    }
    // digits: TPB*LM1 = 768 ints; 256 threads x 3, coalesced
    {
        const long lim = (long)n * LM1;
#pragma unroll
        for (int r = 0; r < (TPB * LM1) / 256; ++r) {
            const int i = tid + r * 256;
            long gi = (long)tok0 * LM1 + i;
            if (gi >= lim) gi = lim - 1;
            sDig[i] = digits[gi];
        }
    }

    // Position weights 1/(i+2)^kappa (uniform; tiny VALU).
    const int k = *kappa_p;
    float w[LM1];
#pragma unroll
    for (int i = 0; i < LM1; ++i) {
        float p = 1.0f;
        const float b = (float)(i + 2);
        for (int j = 0; j < k; ++j) p *= b;
        w[i] = 1.0f / p;
    }

    __syncthreads();

    const int q  = tid & 31;          // float4 slot within the D=128 row
    const int h  = (tid >> 5) & 1;    // half-wave: adjacent tokens within a wave
    const int wv = tid >> 6;          // wave id 0..3

#pragma unroll 2
    for (int c = 0; c < NCHUNK; ++c) {
        int     lt[TPT];
        nfloat4 base[TPT];

        // Phase A: issue lab gathers early (exec-masked; uniform per half-wave).
#pragma unroll
        for (int j = 0; j < TPT; ++j) {
            lt[j] = c * 32 + wv * 8 + j * 2 + h;   // halves hold adjacent tokens
            if (sMod[lt[j]] == 2) {
                const int fidx = sFidx[lt[j]];
                base[j] = *reinterpret_cast<const nfloat4*>(
                    E1 + (size_t)fidx * D + q * 4);
            }
        }
        // Phase B: LDS base rows for icd/atc tokens.
#pragma unroll
        for (int j = 0; j < TPT; ++j) {
            if (sMod[lt[j]] != 2) {
                base[j] = *reinterpret_cast<const nfloat4*>(
                    &sE1[sFidx[lt[j]] - E1LO][q * 4]);
            }
        }
        // Phase C: accumulate + store (1 KB contiguous per wave store instr).
#pragma unroll
        for (int j = 0; j < TPT; ++j) {
            const int lt_ = lt[j];
            nfloat4 acc;
            if (sMod[lt_] == 2) {
                acc = base[j] * sVal[lt_];
            } else {
                acc = base[j];
                const int nd = sNd[lt_];
#pragma unroll
                for (int i = 0; i < LM1; ++i) {
                    if (i < nd) {      // uniform across the 32 lanes of a token
                        const int dg = sDig[lt_ * LM1 + i];
                        acc += w[i] * *reinterpret_cast<const nfloat4*>(
                                          &sEint[dg][q * 4]);
                    }
                }
            }
            const int tok = tok0 + lt_;
            if (tok < n) {
                __builtin_nontemporal_store(
                    acc, reinterpret_cast<nfloat4*>(out + (size_t)tok * D + q * 4));
            }
        }
    }
}

extern "C" void kernel_launch(void* const* d_in, const int* in_sizes, int n_in,
                              void* d_out, int out_size, void* d_ws, size_t ws_size,
                              hipStream_t stream) {
    const int*   first_chars = (const int*)  d_in[0];
    const int*   digits      = (const int*)  d_in[1];
    const int*   ndigits     = (const int*)  d_in[2];
    const int*   mods        = (const int*)  d_in[3];
    const float* vals        = (const float*)d_in[4];
    const float* E1          = (const float*)d_in[5];
    const float* Eint        = (const float*)d_in[6];
    const int*   kappa       = (const int*)  d_in[7];
    float*       out         = (float*)d_out;

    const int n    = in_sizes[0];                 // tokens
    const int grid = (n + TPB - 1) / TPB;         // 2048 blocks at N=262144

    hier_emb_kernel<<<grid, 256, 0, stream>>>(
        first_chars, digits, ndigits, mods, vals, E1, Eint, kappa, out, n);
}

// Round 10
// 161.539 us; speedup vs baseline: 1.1195x; 1.1195x over previous
//
#include <hip/hip_runtime.h>
#include <hip/hip_bf16.h>

// HierarchicalEmbedding.
// out[n,:] = mods==2 ? E1[fidx]*vals : E1[fidx] + sum_{i<nd} w[i]*Eint[dig_i]
// Unified: out = E1[fidx]*val + sum_{i<nd_eff} w[i]*Eint[dig_i]
//   lab: val=vals[t], nd_eff=0;  icd/atc: val=1.0, nd_eff=ndigits[t].
//
// R10 == R9 resubmit (infra failure). Revert R8's E1-LDS (regression).
// Attack latency/occupancy/LDS-instr:
//  - per-token metadata packed in ONE int4 {fidx, dig4b, nd_eff, val_bits}
//    -> 1 ds_read_b128/token in hot loop (was ~10 scalar reads), branchless.
//  - __launch_bounds__(256,8): <=64 VGPR -> 8 waves/SIMD.
//  - depth-2 pipeline: prefetch next group's E1 gathers during accumulate.
//  - wave halves own adjacent tokens -> each store = 1KB contiguous.

#define LM1 6
#define D   128
#define TPB 128

typedef float nfloat4 __attribute__((ext_vector_type(4)));
typedef int   nint4   __attribute__((ext_vector_type(4)));

__global__ __launch_bounds__(256, 8) void hier_emb_kernel(
    const int*   __restrict__ first_chars,
    const int*   __restrict__ digits,
    const int*   __restrict__ ndigits,
    const int*   __restrict__ mods,
    const float* __restrict__ vals,
    const float* __restrict__ E1,
    const float* __restrict__ Eint,
    const int*   __restrict__ kappa_p,
    float*       __restrict__ out,
    int n)
{
    __shared__ float sEint[10][D];     // 5 KB
    __shared__ nint4 sMeta[TPB];       // 2 KB: {fidx, packed_digits, nd_eff, val_bits}
    __shared__ int   sDig[TPB * LM1];  // 3 KB

    const int tid  = threadIdx.x;
    const int tok0 = blockIdx.x * TPB;

    // --- Stage Eint: 320 float4 ---
    {
        const nfloat4* src = reinterpret_cast<const nfloat4*>(Eint);
        nfloat4*       dst = reinterpret_cast<nfloat4*>(&sEint[0][0]);
        dst[tid] = src[tid];
        const int i2 = 256 + tid;
        if (i2 < (10 * D) / 4) dst[i2] = src[i2];
    }
    // --- Stage digits coalesced: 768 ints, 3 rounds ---
    {
        const long lim = (long)n * LM1;
#pragma unroll
        for (int r = 0; r < (TPB * LM1) / 256; ++r) {
            const int i = tid + r * 256;
            long gi = (long)tok0 * LM1 + i;
            if (gi >= lim) gi = lim - 1;
            sDig[i] = digits[gi];
        }
    }
    // --- Scalar metadata (threads 0..127, coalesced) ---
    if (tid < TPB) {
        int tt = tok0 + tid; if (tt >= n) tt = n - 1;
        const int mod  = mods[tt];
        const int fc   = first_chars[tt];
        const int fidx = (mod == 0) ? fc + 5 : (mod == 1) ? fc * 2 + 5 : 52 + fc;
        const int nd   = (mod == 2) ? 0 : ndigits[tt];
        const float v  = (mod == 2) ? vals[tt] : 1.0f;
        nint4 m; m.x = fidx; m.y = 0; m.z = nd; m.w = __float_as_int(v);
        sMeta[tid] = m;
    }

    // Position weights 1/(i+2)^kappa.
    const int k = *kappa_p;
    float w[LM1];
#pragma unroll
    for (int i = 0; i < LM1; ++i) {
        float p = 1.0f;
        const float b = (float)(i + 2);
        for (int j = 0; j < k; ++j) p *= b;
        w[i] = 1.0f / p;
    }

    __syncthreads();

    // --- Pack each token's 6 digits into 4-bit fields of sMeta[t].y ---
    if (tid < TPB) {
        int pd = 0;
#pragma unroll
        for (int i = 0; i < LM1; ++i) pd |= sDig[tid * LM1 + i] << (4 * i);
        reinterpret_cast<int*>(sMeta)[tid * 4 + 1] = pd;
    }
    __syncthreads();

    const int q4 = (tid & 31) * 4;       // float offset within the D=128 row
    const int h  = (tid >> 5) & 1;       // half-wave
    const int wv = tid >> 6;             // wave 0..3
    const int tb = wv * 32;              // wave's local token base

    const float* E1Q   = E1 + q4;
    const float* EintQ = &sEint[0][q4];
    float*       outQ  = out + q4;

    // Per group g: thread handles local tokens (tb+g*4+h) and (tb+g*4+h+2).
    // Store #A covers tokens {+0,+1} (1KB contiguous), store #B {+2,+3}.

    // Prologue: group 0 metadata + gathers.
    nint4 m0 = sMeta[tb + h];
    nint4 m1 = sMeta[tb + h + 2];
    nfloat4 b0 = *reinterpret_cast<const nfloat4*>(E1Q + (size_t)m0.x * D);
    nfloat4 b1 = *reinterpret_cast<const nfloat4*>(E1Q + (size_t)m1.x * D);

#pragma unroll
    for (int g = 0; g < 8; ++g) {
        // Prefetch group g+1 (LDS meta -> 2 independent E1 gathers).
        nint4 p0, p1; nfloat4 c0, c1;
        if (g < 7) {
            const int ln = tb + (g + 1) * 4 + h;
            p0 = sMeta[ln];
            p1 = sMeta[ln + 2];
            c0 = *reinterpret_cast<const nfloat4*>(E1Q + (size_t)p0.x * D);
            c1 = *reinterpret_cast<const nfloat4*>(E1Q + (size_t)p1.x * D);
        }

        const int ltA = tb + g * 4 + h;
        // Token A
        {
            nfloat4 acc = b0 * __int_as_float(m0.w);
            const int nd = m0.z, pd = m0.y;
#pragma unroll
            for (int i = 0; i < LM1; ++i) {
                if (i < nd) {
                    const int dg = (pd >> (4 * i)) & 15;
                    acc += w[i] * *reinterpret_cast<const nfloat4*>(EintQ + dg * D);
                }
            }
            const int tok = tok0 + ltA;
            if (tok < n)
                __builtin_nontemporal_store(
                    acc, reinterpret_cast<nfloat4*>(outQ + (size_t)tok * D));
        }
        // Token B (= A + 2)
        {
            nfloat4 acc = b1 * __int_as_float(m1.w);
            const int nd = m1.z, pd = m1.y;
#pragma unroll
            for (int i = 0; i < LM1; ++i) {
                if (i < nd) {
                    const int dg = (pd >> (4 * i)) & 15;
                    acc += w[i] * *reinterpret_cast<const nfloat4*>(EintQ + dg * D);
                }
            }
            const int tok = tok0 + ltA + 2;
            if (tok < n)
                __builtin_nontemporal_store(
                    acc, reinterpret_cast<nfloat4*>(outQ + (size_t)tok * D));
        }
        m0 = p0; m1 = p1; b0 = c0; b1 = c1;
    }
}

extern "C" void kernel_launch(void* const* d_in, const int* in_sizes, int n_in,
                              void* d_out, int out_size, void* d_ws, size_t ws_size,
                              hipStream_t stream) {
    const int*   first_chars = (const int*)  d_in[0];
    const int*   digits      = (const int*)  d_in[1];
    const int*   ndigits     = (const int*)  d_in[2];
    const int*   mods        = (const int*)  d_in[3];
    const float* vals        = (const float*)d_in[4];
    const float* E1          = (const float*)d_in[5];
    const float* Eint        = (const float*)d_in[6];
    const int*   kappa       = (const int*)  d_in[7];
    float*       out         = (float*)d_out;

    const int n    = in_sizes[0];                 // tokens
    const int grid = (n + TPB - 1) / TPB;         // 2048 blocks at N=262144

    hier_emb_kernel<<<grid, 256, 0, stream>>>(
        first_chars, digits, ndigits, mods, vals, E1, Eint, kappa, out, n);
}